// Round 9
// baseline (49.031 us; speedup 1.0000x reference)
//
#include <hip/hip_runtime.h>

typedef unsigned long long u64;
typedef unsigned int u32;

#define BATCH 64
#define CH    64
#define HH    56
#define WW    56
#define HW    3136
#define NBAND 14                // 4-row bands per image
#define NBLK  (BATCH * NBAND)   // 896 = 8*112

// Kernel 1 (tiny, 64 blocks): per-p weight fold.
// wtab record [p][12] u64: [0..8] = packed sign bits (bit c = w[p][c][t] > 0),
//                          [9..10] = {-2am, alpha, b2, 0} f32x4, [11] = pad.
// kc[9][64]: class-folded constant k = am*(64*nvalid + 2*Cinv) + bd,
//            class = wclass*3 + lclass (h-edge x w-edge).
__global__ __launch_bounds__(256)
void fold_kernel(const float* __restrict__ w,
                 const float* __restrict__ gamma,
                 const float* __restrict__ beta,
                 const float* __restrict__ rmean,
                 const float* __restrict__ rvar,
                 const float* __restrict__ bias1,
                 const float* __restrict__ alpha,
                 const float* __restrict__ bias2,
                 u64* __restrict__ wtab,
                 float* __restrict__ kc) {
    __shared__ float red[4];
    const int tid = threadIdx.x;
    const int lane = tid & 63;
    const int wv = tid >> 6;
    const int p = blockIdx.x;
    const float* wp = w + p * 576;

    float s = 0.f;
    for (int i = tid; i < 576; i += 256) s += fabsf(wp[i]);
#pragma unroll
    for (int off = 32; off > 0; off >>= 1) s += __shfl_down(s, off);
    if (lane == 0) red[wv] = s;
    __syncthreads();

    if (wv == 0) {
        u64 m[9];
#pragma unroll
        for (int t = 0; t < 9; ++t) {
            m[t] = __ballot(wp[lane * 9 + t] > 0.f);
            if (lane == 0) wtab[p * 12 + t] = m[t];
        }
        if (lane == 0) {
            float scale = (red[0] + red[1] + red[2] + red[3]) * (1.0f / 576.0f);
            float inv = gamma[p] * rsqrtf(rvar[p] + 1e-5f);
            float am = scale * inv;
            float bd = beta[p] - rmean[p] * inv + bias1[p];
            float pt[9];
#pragma unroll
            for (int t = 0; t < 9; ++t) pt[t] = (float)__popcll(m[t]);
            const float cL = pt[0] + pt[3] + pt[6];
            const float cR = pt[2] + pt[5] + pt[8];
            const float rT = pt[0] + pt[1] + pt[2];
            const float rB = pt[6] + pt[7] + pt[8];
            float Ci[3][3] = {
                {0.f, cL,                 cR},
                {rT,  rT + pt[3] + pt[6], rT + pt[5] + pt[8]},
                {rB,  rB + pt[0] + pt[3], rB + pt[2] + pt[5]}};
            float nv[3][3] = {{9, 6, 6}, {6, 4, 4}, {6, 4, 4}};
#pragma unroll
            for (int wc = 0; wc < 3; ++wc)
#pragma unroll
                for (int lc = 0; lc < 3; ++lc)
                    kc[(wc * 3 + lc) * 64 + p] =
                        fmaf(am, 64.f * nv[wc][lc] + 2.f * Ci[wc][lc], bd);
            float* cf = (float*)(wtab + p * 12 + 9);
            cf[0] = -2.f * am;
            cf[1] = alpha[p];
            cf[2] = bias2[p];
            cf[3] = 0.f;
            wtab[p * 12 + 11] = 0;
        }
    }
}

// Kernel 2: fully fused sign-pack + XNOR-popcount conv + epilogue.
// Block = 512 thr (8 waves) = one (b, 4-row band). x read ONCE from HBM.
//  Phase 1: waves 0..5 ballot-pack rows r0-1..r0+4 into Lsgn[6][58] (zero-padded).
//  Phase 2: wave (wv&3, wv>>2) = row r0+(wv&3), channels (wv>>2)*32..+31.
//           Weights/epilogue consts via wave-uniform s_load records;
//           residual via rolling 8-deep prefetch (res[i&7], static under unroll).
__global__ __launch_bounds__(512, 6)
void fused_kernel(const float* __restrict__ x,
                  const float* __restrict__ bias0,
                  const u64* __restrict__ wtab,
                  const float* __restrict__ kc,
                  float* __restrict__ out) {
    __shared__ __align__(16) u64 Lsgn[6][58];
    __shared__ float kcsm[576];

    const int tid = threadIdx.x;
    const int lane = tid & 63;
    const int wv = tid >> 6;

    for (int i = tid; i < 576; i += 512) kcsm[i] = kc[i];

    // bijective XCD swizzle: 896 = 8*112; adjacent bands share halo rows in L2
    const int bid = blockIdx.x;
    const int wg = (bid & 7) * 112 + (bid >> 3);
    const int b = wg / NBAND;
    const int band = wg - b * NBAND;
    const int r0 = band * 4;

    // ---- Phase 1: pack 6 sign rows (lane = channel, ballot per w) ----
    if (wv < 6) {
        const int ir = r0 - 1 + wv;
        const bool rowok = (unsigned)ir < (unsigned)HH;   // wave-uniform
        u64 mine = 0;
        if (rowok) {
            const float* xp = x + ((size_t)(b * CH + lane)) * HW + ir * WW;
            const float bz = bias0[lane];
#pragma unroll
            for (int q = 0; q < 14; ++q) {
                float4 v = *(const float4*)(xp + q * 4);
                u64 m0 = __ballot(v.x + bz > 0.f);
                u64 m1 = __ballot(v.y + bz > 0.f);
                u64 m2 = __ballot(v.z + bz > 0.f);
                u64 m3 = __ballot(v.w + bz > 0.f);
                mine = (lane == q * 4 + 0) ? m0 : mine;
                mine = (lane == q * 4 + 1) ? m1 : mine;
                mine = (lane == q * 4 + 2) ? m2 : mine;
                mine = (lane == q * 4 + 3) ? m3 : mine;
            }
        }
        if (lane < WW)        Lsgn[wv][1 + lane] = mine;
        else if (lane == 56)  Lsgn[wv][0] = 0;
        else if (lane == 57)  Lsgn[wv][57] = 0;
    }
    __syncthreads();

    // ---- Phase 2 ----
    const int rl = wv & 3;
    const int ph = __builtin_amdgcn_readfirstlane((wv >> 2) << 5);  // 0 or 32
    const int h = r0 + rl;
    const int wl = min(lane, WW - 1);
    const bool active = lane < WW;

    u64 a[9];
#pragma unroll
    for (int t = 0; t < 9; ++t)
        a[t] = Lsgn[rl + t / 3][wl + t % 3];   // zero pads: unconditional

    const int wclass = (h == 0) ? 1 : (h == HH - 1) ? 2 : 0;
    const int lclass = (lane == 0) ? 1 : (lane == WW - 1) ? 2 : 0;
    const float* kp = kcsm + (wclass * 3 + lclass) * 64 + ph;

    // 32-bit element offset (x/out span 12.85M elems < 2^32)
    u32 off = (u32)(b * CH * HW + h * WW + wl) + (u32)ph * HW;
    const u64* wp = wtab + ph * 12;            // wave-uniform -> s_load records

    // rolling 8-deep residual prefetch; res[i&7] is static under full unroll
    float res[8];
#pragma unroll
    for (int j = 0; j < 8; ++j) res[j] = x[off + (u32)j * HW];

#pragma unroll
    for (int i = 0; i < 32; ++i) {
        const float rcur = res[i & 7];
        if (i + 8 < 32) res[i & 7] = x[off + 8u * HW];  // channel ph+i+8 (off is loop-relative)

        u32 P = 0;
        u64 v;
        v = a[0] ^ wp[0]; P += __popc((u32)v); P += __popc((u32)(v >> 32));
        v = a[1] ^ wp[1]; P += __popc((u32)v); P += __popc((u32)(v >> 32));
        v = a[2] ^ wp[2]; P += __popc((u32)v); P += __popc((u32)(v >> 32));
        v = a[3] ^ wp[3]; P += __popc((u32)v); P += __popc((u32)(v >> 32));
        v = a[4] ^ wp[4]; P += __popc((u32)v); P += __popc((u32)(v >> 32));
        v = a[5] ^ wp[5]; P += __popc((u32)v); P += __popc((u32)(v >> 32));
        v = a[6] ^ wp[6]; P += __popc((u32)v); P += __popc((u32)(v >> 32));
        v = a[7] ^ wp[7]; P += __popc((u32)v); P += __popc((u32)(v >> 32));
        v = a[8] ^ wp[8]; P += __popc((u32)v); P += __popc((u32)(v >> 32));

        const float* cf = (const float*)(wp + 9);   // {-2am, al, b2} uniform
        const float k = kp[i];                      // broadcast ds_read
        float o = fmaf(cf[0], (float)P, k) + rcur;
        o = o >= 0.f ? o : cf[1] * o;
        o += cf[2];
        if (active) out[off] = o;

        off += HW;
        wp += 12;
    }
}

extern "C" void kernel_launch(void* const* d_in, const int* in_sizes, int n_in,
                              void* d_out, int out_size, void* d_ws, size_t ws_size,
                              hipStream_t stream) {
    const float* x     = (const float*)d_in[0];
    const float* bias0 = (const float*)d_in[1];
    const float* w     = (const float*)d_in[2];
    const float* gamma = (const float*)d_in[3];
    const float* beta  = (const float*)d_in[4];
    const float* rmean = (const float*)d_in[5];
    const float* rvar  = (const float*)d_in[6];
    const float* bias1 = (const float*)d_in[7];
    const float* alpha = (const float*)d_in[8];
    const float* bias2 = (const float*)d_in[9];
    float* out = (float*)d_out;

    char* ws = (char*)d_ws;
    u64* wtab = (u64*)ws;                  // 64*12*8 = 6,144 B
    float* kc = (float*)(ws + 6144);       // 9*64*4  = 2,304 B

    fold_kernel<<<64, 256, 0, stream>>>(
        w, gamma, beta, rmean, rvar, bias1, alpha, bias2, wtab, kc);

    fused_kernel<<<NBLK, 512, 0, stream>>>(x, bias0, wtab, kc, out);
}